// Round 1
// baseline (258.642 us; speedup 1.0000x reference)
//
#include <hip/hip_runtime.h>

#define N_L 256
#define N_Q 65536
#define D_IN 384
#define D_CTX 192
#define HDIM 64
#define MAXA 6

typedef float v2f __attribute__((ext_vector_type(2)));

__device__ __forceinline__ v2f mk2(float a, float b) { v2f r; r.x = a; r.y = b; return r; }

__device__ __forceinline__ void fma4(float& acc, const float4& w, const float4& v) {
    acc = fmaf(w.x, v.x, acc);
    acc = fmaf(w.y, v.y, acc);
    acc = fmaf(w.z, v.z, acc);
    acc = fmaf(w.w, v.w, acc);
}

__device__ __forceinline__ float lgfact(int n) {
    // log(n!) for n in 0..6  (== gammaln(n+1))
    return (n <= 1) ? 0.0f :
           (n == 2) ? 0.6931471805599453f :
           (n == 3) ? 1.7917594692280550f :
           (n == 4) ? 3.1780538303479458f :
           (n == 5) ? 4.7874917427820460f :
                      6.5792512120101010f;
}

// ---------------- DPP wave reduction helpers (VALU pipe, no LDS traffic) ----------------
template<int CTRL, int RM, bool BC>
__device__ __forceinline__ float dppz(float x) {   // old = 0 (masked/invalid lanes contribute 0)
    return __int_as_float(__builtin_amdgcn_update_dpp(0, __float_as_int(x), CTRL, RM, 0xF, BC));
}
template<int CTRL, int RM>
__device__ __forceinline__ float dpps(float x) {   // old = x (identity for max)
    int xi = __float_as_int(x);
    return __int_as_float(__builtin_amdgcn_update_dpp(xi, xi, CTRL, RM, 0xF, false));
}
// inclusive prefix-sum across 64 lanes; lane 63 ends with the wave total
__device__ __forceinline__ float wave_iscan(float t) {
    t += dppz<0x111, 0xF, true>(t);    // row_shr:1, 0-fill
    t += dppz<0x112, 0xF, true>(t);    // row_shr:2
    t += dppz<0x114, 0xF, true>(t);    // row_shr:4
    t += dppz<0x118, 0xF, true>(t);    // row_shr:8
    t += dppz<0x142, 0xA, false>(t);   // row_bcast:15 -> rows 1,3
    t += dppz<0x143, 0xC, false>(t);   // row_bcast:31 -> rows 2,3
    return t;
}
// wave max; lane 63 ends with the full 64-lane max (exact, max is associative)
__device__ __forceinline__ float wave_max_l63(float m) {
    m = fmaxf(m, dpps<0x111, 0xF>(m));
    m = fmaxf(m, dpps<0x112, 0xF>(m));
    m = fmaxf(m, dpps<0x114, 0xF>(m));
    m = fmaxf(m, dpps<0x118, 0xF>(m));
    m = fmaxf(m, dpps<0x142, 0xA>(m));
    m = fmaxf(m, dpps<0x143, 0xC>(m));
    return m;
}
__device__ __forceinline__ float bc63(float x) {   // broadcast lane 63 via SGPR
    return __int_as_float(__builtin_amdgcn_readlane(__float_as_int(x), 63));
}

// ---------------- packed fp32 FMA with op_sel broadcast of one half of src1 ----------------
// d.lo += a.lo * b.lo ; d.hi += a.hi * b.lo
__device__ __forceinline__ void pk_fma_lo(v2f& d, v2f a, v2f b) {
    asm("v_pk_fma_f32 %0, %1, %2, %0 op_sel:[0,0,0] op_sel_hi:[1,0,1]"
        : "+v"(d) : "v"(a), "v"(b));
}
// d.lo += a.lo * b.hi ; d.hi += a.hi * b.hi
__device__ __forceinline__ void pk_fma_hi(v2f& d, v2f a, v2f b) {
    asm("v_pk_fma_f32 %0, %1, %2, %0 op_sel:[0,1,0] op_sel_hi:[1,1,1]"
        : "+v"(d) : "v"(a), "v"(b));
}

// ---------------- Kernel 1: VAE + llm embT + packed ctx_w transpose + loss partials ----
__global__ __launch_bounds__(64) void vae_kernel(
    const float* __restrict__ llms, const float* __restrict__ ctx_w,
    const float* __restrict__ fc1_w, const float* __restrict__ fc1_b,
    const float* __restrict__ fc21_w, const float* __restrict__ fc21_b,
    const float* __restrict__ fc22_w, const float* __restrict__ fc22_b,
    const float* __restrict__ fc3_w, const float* __restrict__ fc3_b,
    const float* __restrict__ fc4_w, const float* __restrict__ fc4_b,
    const float* __restrict__ eps,
    float* __restrict__ ctx_wP, float* __restrict__ embT,
    float* __restrict__ mse_row, float* __restrict__ kld_row)
{
    __shared__ __align__(16) float xs[D_IN];
    __shared__ __align__(16) float hs[HDIM];
    __shared__ __align__(16) float zs[HDIM];
    __shared__ __align__(16) float h2s[HDIM];
    const int r = blockIdx.x;
    const int j = threadIdx.x;

    // side job: pack-transpose ctx_w -> ctx_wP[(k4*64+j)*4+rr] = ctx_w[j*192+k4*4+rr]
    {
        int f = r * 64 + j;                       // [0, 16384); need [0, 12288)
        if (f < D_CTX * HDIM) {
            int p = f >> 2, rr = f & 3;
            int jc = p & 63, k4 = p >> 6;
            ctx_wP[f] = ctx_w[jc * D_CTX + k4 * 4 + rr];
        }
    }

    for (int k = j; k < D_IN; k += 64) xs[k] = llms[r * D_IN + k];
    __syncthreads();

    float acc = fc1_b[j];
    {
        const float4* wr = (const float4*)(fc1_w + (size_t)j * D_IN);
        const float4* xr = (const float4*)xs;
        #pragma unroll 8
        for (int k4 = 0; k4 < D_IN / 4; ++k4) { fma4(acc, wr[k4], xr[k4]); }
    }
    float h = fmaxf(acc, 0.0f);
    hs[j] = h;
    __syncthreads();

    float mu = fc21_b[j], lv = fc22_b[j];
    {
        const float4* w1 = (const float4*)(fc21_w + (size_t)j * HDIM);
        const float4* w2 = (const float4*)(fc22_w + (size_t)j * HDIM);
        const float4* hr = (const float4*)hs;
        #pragma unroll
        for (int k4 = 0; k4 < HDIM / 4; ++k4) {
            float4 hh = hr[k4];
            fma4(mu, w1[k4], hh);
            fma4(lv, w2[k4], hh);
        }
    }
    float stdv = expf(0.5f * lv) * 0.1f;
    float z = fmaf(eps[r * HDIM + j], stdv, mu);

    float elv = expf(lv);
    float kt = (1.0f - (-4.60517018598809136f)) + lv - (mu * mu + elv) / 0.01f;
    float ks = kt;
    #pragma unroll
    for (int o = 32; o; o >>= 1) ks += __shfl_xor(ks, o);

    float zsq = z * z;
    #pragma unroll
    for (int o = 32; o; o >>= 1) zsq += __shfl_xor(zsq, o);
    float nrm = fmaxf(sqrtf(zsq), 1e-12f);
    embT[j * N_L + r] = z / nrm;                 // transposed store (one-time scatter)
    zs[j] = z;
    __syncthreads();

    float a3 = fc3_b[j];
    {
        const float4* w3 = (const float4*)(fc3_w + (size_t)j * HDIM);
        const float4* zr = (const float4*)zs;
        #pragma unroll
        for (int k4 = 0; k4 < HDIM / 4; ++k4) { fma4(a3, w3[k4], zr[k4]); }
    }
    float h2 = fmaxf(a3, 0.0f);
    h2s[j] = h2;
    __syncthreads();

    float ms = 0.0f;
    const float4* h2r = (const float4*)h2s;
    #pragma unroll
    for (int m = 0; m < 6; ++m) {
        int o = j + 64 * m;
        float a4 = fc4_b[o];
        const float4* w4 = (const float4*)(fc4_w + (size_t)o * HDIM);
        #pragma unroll
        for (int k4 = 0; k4 < HDIM / 4; ++k4) { fma4(a4, w4[k4], h2r[k4]); }
        float d = a4 - xs[o];
        ms = fmaf(d, d, ms);
    }
    #pragma unroll
    for (int o = 32; o; o >>= 1) ms += __shfl_xor(ms, o);
    if (j == 0) { mse_row[r] = ms; kld_row[r] = ks; }
}

// ---------------- Kernel 2: FUSED routing ------------------------------------------------
// x-tile and uniforms now come in via wave-uniform SCALAR loads (s_load / K-cache), which
// feed v_fma as the scalar operand directly — LDS holds only the 512-float e-strip per wave.
// All reductions/scans run on the VALU via DPP (row_shr + row_bcast), zero LDS traffic.
// FMAs are issued as v_pk_fma_f32 (packed fp32, full rate): phase 2 is bit-identical in
// per-component accumulation order to the previous (passing) kernel.
__global__ __launch_bounds__(256) void route_kernel(
    const float* __restrict__ contexts, const float* __restrict__ ctx_wP, const float* __restrict__ ctx_b,
    const float* __restrict__ embT, const int* __restrict__ agent_num, const float* __restrict__ rand_u,
    const float* __restrict__ mse_row, const float* __restrict__ kld_row,
    float* __restrict__ out_sel, float* __restrict__ out_lp, float* __restrict__ out_loss)
{
    __shared__ __align__(16) float lds[4][512];          // e-strips only: 8 KB/block

    const int tid = threadIdx.x;
    const int lane = tid & 63;
    const int widx = tid >> 6;
    const int l0 = lane << 2;

    const int g = blockIdx.x * 4 + widx;                 // wave id [0, 8192)
    const int q0 = __builtin_amdgcn_readfirstlane(g << 3);
    float* myl = lds[widx];

    // ---- fold in vae_loss finalize (wave 0 only) ----
    if (g == 0) {
        int rr = lane * 4;
        float ms = mse_row[rr] + mse_row[rr + 1] + mse_row[rr + 2] + mse_row[rr + 3];
        float ks = kld_row[rr] + kld_row[rr + 1] + kld_row[rr + 2] + kld_row[rr + 3];
        #pragma unroll
        for (int o = 32; o; o >>= 1) { ms += __shfl_xor(ms, o); ks += __shfl_xor(ks, o); }
        if (lane == 0) out_loss[0] = ms / 98304.0f - 0.5f * (ks / 16384.0f);
    }

    // ---- agent counts: wave-uniform index -> scalar loads ----
    int Aq[8];
    #pragma unroll
    for (int q = 0; q < 8; ++q) Aq[q] = agent_num[q0 + q];

    // ---- phase 1: e_j (lane j) for 8 queries; w coalesced b128, x via uniform s_load ----
    const float bj = ctx_b[lane];
    v2f acc[8];
    #pragma unroll
    for (int q = 0; q < 8; ++q) acc[q] = mk2(bj, 0.0f);
    {
        const float4* wp = (const float4*)ctx_wP;
        const float4* xb = (const float4*)(contexts + (size_t)q0 * D_CTX);
        #pragma unroll 2
        for (int k4 = 0; k4 < D_CTX / 4; ++k4) {
            float4 w = wp[k4 * HDIM + lane];             // lane-coalesced 1 KB load
            v2f w01 = mk2(w.x, w.y), w23 = mk2(w.z, w.w);
            #pragma unroll
            for (int q = 0; q < 8; ++q) {
                float4 xv = xb[q * (D_CTX / 4) + k4];    // wave-uniform -> s_load_dwordx4
                acc[q] = __builtin_elementwise_fma(w01, mk2(xv.x, xv.y), acc[q]);
                acc[q] = __builtin_elementwise_fma(w23, mk2(xv.z, xv.w), acc[q]);
            }
        }
    }
    float e[8];
    #pragma unroll
    for (int q = 0; q < 8; ++q) e[q] = acc[q].x + acc[q].y;
    #pragma unroll
    for (int q = 0; q < 8; ++q) {
        float s = bc63(wave_iscan(e[q] * e[q]));         // wave sum via DPP -> SGPR
        e[q] *= 1.0f / fmaxf(sqrtf(s), 1e-12f);
        myl[q * HDIM + lane] = e[q];                     // e-strip (conflict-free write)
    }

    // ---- phase 2: logits, lane's 4 llms x 8 queries; packed fp32, op_sel e-broadcast ----
    v2f Pa[8], Pb[8];                                    // (l0,l0+1) and (l0+2,l0+3)
    #pragma unroll
    for (int q = 0; q < 8; ++q) { Pa[q] = mk2(0.0f, 0.0f); Pb[q] = mk2(0.0f, 0.0f); }

    #pragma unroll 2
    for (int j4 = 0; j4 < HDIM / 4; ++j4) {
        float4 M0 = *(const float4*)(embT + (size_t)(j4 * 4 + 0) * N_L + l0);  // coalesced
        float4 M1 = *(const float4*)(embT + (size_t)(j4 * 4 + 1) * N_L + l0);
        float4 M2 = *(const float4*)(embT + (size_t)(j4 * 4 + 2) * N_L + l0);
        float4 M3 = *(const float4*)(embT + (size_t)(j4 * 4 + 3) * N_L + l0);
        v2f m0a = mk2(M0.x, M0.y), m0b = mk2(M0.z, M0.w);
        v2f m1a = mk2(M1.x, M1.y), m1b = mk2(M1.z, M1.w);
        v2f m2a = mk2(M2.x, M2.y), m2b = mk2(M2.z, M2.w);
        v2f m3a = mk2(M3.x, M3.y), m3b = mk2(M3.z, M3.w);
        #pragma unroll
        for (int q = 0; q < 8; ++q) {
            float4 ev = *(const float4*)(myl + q * HDIM + j4 * 4);   // uniform LDS broadcast
            v2f e01 = mk2(ev.x, ev.y), e23 = mk2(ev.z, ev.w);
            // per-component order identical to prior rounds: M0*ev.x, M1*ev.y, M2*ev.z, M3*ev.w
            pk_fma_lo(Pa[q], m0a, e01);
            pk_fma_hi(Pa[q], m1a, e01);
            pk_fma_lo(Pa[q], m2a, e23);
            pk_fma_hi(Pa[q], m3a, e23);
            pk_fma_lo(Pb[q], m0b, e01);
            pk_fma_hi(Pb[q], m1b, e01);
            pk_fma_lo(Pb[q], m2b, e23);
            pk_fma_hi(Pb[q], m3b, e23);
        }
    }

    float4 P[8];
    #pragma unroll
    for (int k = 0; k < 8; ++k) P[k] = make_float4(Pa[k].x, Pa[k].y, Pb[k].x, Pb[k].y);

    // ---- softmax (DPP max/sum; same per-query op order) ----
    #pragma unroll
    for (int k = 0; k < 8; ++k) {
        float m = fmaxf(fmaxf(P[k].x, P[k].y), fmaxf(P[k].z, P[k].w));
        m = bc63(wave_max_l63(m));                       // exact wave max
        P[k].x = expf(P[k].x - m); P[k].y = expf(P[k].y - m);
        P[k].z = expf(P[k].z - m); P[k].w = expf(P[k].w - m);
        float s = bc63(wave_iscan(P[k].x + P[k].y + P[k].z + P[k].w));
        float inv = 1.0f / s;
        P[k].x *= inv; P[k].y *= inv; P[k].z *= inv; P[k].w *= inv;
    }

    // ---- inclusive cumsum via DPP scan ----
    float c0[8], c1[8], c2[8], c3[8];
    #pragma unroll
    for (int k = 0; k < 8; ++k) {
        c0[k] = P[k].x; c1[k] = c0[k] + P[k].y; c2[k] = c1[k] + P[k].z;
        float p3 = c2[k] + P[k].w;
        float t = wave_iscan(p3);
        float base = t - p3;
        c0[k] += base; c1[k] += base; c2[k] += base; c3[k] = p3 + base;
    }

    // ---- sampling: ballot+popcount; u via wave-uniform scalar load ----
    unsigned nib[8] = {0, 0, 0, 0, 0, 0, 0, 0};
    #pragma unroll
    for (int i = 0; i < MAXA; ++i) {
        #pragma unroll
        for (int k = 0; k < 8; ++k) {
            if (i < Aq[k]) {                       // wave-uniform scalar branch
                float u = rand_u[(size_t)i * N_Q + q0 + k];   // uniform -> s_load
                unsigned long long b0 = __ballot(c0[k] <= u);
                unsigned long long b1 = __ballot(c1[k] <= u);
                unsigned long long b2 = __ballot(c2[k] <= u);
                unsigned long long b3 = __ballot(c3[k] <= u);
                int loc = __popcll(b0) + __popcll(b1) + __popcll(b2) + __popcll(b3);
                int sel = (loc >= N_L) ? 0 : loc;  // numpy argmax(all-False) == 0
                unsigned d = (unsigned)(sel - l0);
                if (d < 4u) nib[k] += 1u << (4 * d);
            }
        }
    }

    // ---- row stores + log-prob terms (same per-query arithmetic/order) ----
    float term[8];
    #pragma unroll
    for (int k = 0; k < 8; ++k) {
        int n0 = nib[k] & 15, n1 = (nib[k] >> 4) & 15, n2 = (nib[k] >> 8) & 15, n3 = (nib[k] >> 12) & 15;
        float4 rowv = make_float4((float)n0, (float)n1, (float)n2, (float)n3);
        *(((float4*)(out_sel + (size_t)(q0 + k) * N_L)) + lane) = rowv;
        float tm = 0.0f;
        if (n0) tm += (float)n0 * logf(P[k].x) - lgfact(n0);
        if (n1) tm += (float)n1 * logf(P[k].y) - lgfact(n1);
        if (n2) tm += (float)n2 * logf(P[k].z) - lgfact(n2);
        if (n3) tm += (float)n3 * logf(P[k].w) - lgfact(n3);
        term[k] = tm;
    }
    float st[8];
    #pragma unroll
    for (int k = 0; k < 8; ++k) st[k] = bc63(wave_iscan(term[k]));

    if (lane < 8) {
        float rr = st[0];
        int Aa = Aq[0];
        #pragma unroll
        for (int k = 1; k < 8; ++k) {
            if (lane == k) { rr = st[k]; Aa = Aq[k]; }
        }
        out_lp[q0 + lane] = lgfact(Aa) + rr;
    }
}

extern "C" void kernel_launch(void* const* d_in, const int* in_sizes, int n_in,
                              void* d_out, int out_size, void* d_ws, size_t ws_size,
                              hipStream_t stream) {
    const float* llms      = (const float*)d_in[0];
    const float* contexts  = (const float*)d_in[1];
    const int*   agent_i   = (const int*)  d_in[2];
    // d_in[3] agent_num_float unused (int version + table)
    const float* fc1_w  = (const float*)d_in[4];  const float* fc1_b  = (const float*)d_in[5];
    const float* fc21_w = (const float*)d_in[6];  const float* fc21_b = (const float*)d_in[7];
    const float* fc22_w = (const float*)d_in[8];  const float* fc22_b = (const float*)d_in[9];
    const float* fc3_w  = (const float*)d_in[10]; const float* fc3_b  = (const float*)d_in[11];
    const float* fc4_w  = (const float*)d_in[12]; const float* fc4_b  = (const float*)d_in[13];
    const float* ctx_w  = (const float*)d_in[14]; const float* ctx_b  = (const float*)d_in[15];
    const float* noise  = (const float*)d_in[16]; const float* rand_u = (const float*)d_in[17];

    float* out      = (float*)d_out;
    float* out_sel  = out;                          // [65536][256]
    float* out_lp   = out + (size_t)N_Q * N_L;      // [65536]
    float* out_loss = out_lp + N_Q;                 // [1]

    float* ctx_wP   = (float*)d_ws;                 // [48][64] float4 (12288 floats)
    float* embT     = ctx_wP + D_CTX * HDIM;        // [64][256]
    float* mse_row  = embT + HDIM * N_L;            // [256]
    float* kld_row  = mse_row + N_L;                // [256]

    vae_kernel<<<N_L, 64, 0, stream>>>(llms, ctx_w, fc1_w, fc1_b, fc21_w, fc21_b, fc22_w, fc22_b,
                                       fc3_w, fc3_b, fc4_w, fc4_b, noise,
                                       ctx_wP, embT, mse_row, kld_row);
    route_kernel<<<2048, 256, 0, stream>>>(contexts, ctx_wP, ctx_b, embT, agent_i, rand_u,
                                           mse_row, kld_row, out_sel, out_lp, out_loss);
}

// Round 2
// 228.707 us; speedup vs baseline: 1.1309x; 1.1309x over previous
//
#include <hip/hip_runtime.h>

#define N_L 256
#define N_Q 65536
#define D_IN 384
#define D_CTX 192
#define HDIM 64
#define MAXA 6

typedef float v2f __attribute__((ext_vector_type(2)));

__device__ __forceinline__ v2f mk2(float a, float b) { v2f r; r.x = a; r.y = b; return r; }

__device__ __forceinline__ void fma4(float& acc, const float4& w, const float4& v) {
    acc = fmaf(w.x, v.x, acc);
    acc = fmaf(w.y, v.y, acc);
    acc = fmaf(w.z, v.z, acc);
    acc = fmaf(w.w, v.w, acc);
}

__device__ __forceinline__ float lgfact(int n) {
    // log(n!) for n in 0..6  (== gammaln(n+1))
    return (n <= 1) ? 0.0f :
           (n == 2) ? 0.6931471805599453f :
           (n == 3) ? 1.7917594692280550f :
           (n == 4) ? 3.1780538303479458f :
           (n == 5) ? 4.7874917427820460f :
                      6.5792512120101010f;
}

// ---------------- DPP wave reduction helpers (VALU pipe, no LDS traffic) ----------------
template<int CTRL, int RM, bool BC>
__device__ __forceinline__ float dppz(float x) {   // old = 0 (masked/invalid lanes contribute 0)
    return __int_as_float(__builtin_amdgcn_update_dpp(0, __float_as_int(x), CTRL, RM, 0xF, BC));
}
template<int CTRL, int RM>
__device__ __forceinline__ float dpps(float x) {   // old = x (identity for max)
    int xi = __float_as_int(x);
    return __int_as_float(__builtin_amdgcn_update_dpp(xi, xi, CTRL, RM, 0xF, false));
}
// inclusive prefix-sum across 64 lanes; lane 63 ends with the wave total
__device__ __forceinline__ float wave_iscan(float t) {
    t += dppz<0x111, 0xF, true>(t);    // row_shr:1, 0-fill
    t += dppz<0x112, 0xF, true>(t);    // row_shr:2
    t += dppz<0x114, 0xF, true>(t);    // row_shr:4
    t += dppz<0x118, 0xF, true>(t);    // row_shr:8
    t += dppz<0x142, 0xA, false>(t);   // row_bcast:15 -> rows 1,3
    t += dppz<0x143, 0xC, false>(t);   // row_bcast:31 -> rows 2,3
    return t;
}
// wave max; lane 63 ends with the full 64-lane max (exact, max is associative)
__device__ __forceinline__ float wave_max_l63(float m) {
    m = fmaxf(m, dpps<0x111, 0xF>(m));
    m = fmaxf(m, dpps<0x112, 0xF>(m));
    m = fmaxf(m, dpps<0x114, 0xF>(m));
    m = fmaxf(m, dpps<0x118, 0xF>(m));
    m = fmaxf(m, dpps<0x142, 0xA>(m));
    m = fmaxf(m, dpps<0x143, 0xC>(m));
    return m;
}
__device__ __forceinline__ float bc63(float x) {   // broadcast lane 63 via SGPR
    return __int_as_float(__builtin_amdgcn_readlane(__float_as_int(x), 63));
}

// ---------------- packed fp32 FMA with op_sel broadcast of one half of src1 ----------------
// d.lo += a.lo * b.lo ; d.hi += a.hi * b.lo
__device__ __forceinline__ void pk_fma_lo(v2f& d, v2f a, v2f b) {
    asm("v_pk_fma_f32 %0, %1, %2, %0 op_sel:[0,0,0] op_sel_hi:[1,0,1]"
        : "+v"(d) : "v"(a), "v"(b));
}
// d.lo += a.lo * b.hi ; d.hi += a.hi * b.hi
__device__ __forceinline__ void pk_fma_hi(v2f& d, v2f a, v2f b) {
    asm("v_pk_fma_f32 %0, %1, %2, %0 op_sel:[0,1,0] op_sel_hi:[1,1,1]"
        : "+v"(d) : "v"(a), "v"(b));
}

// ---------------- Kernel 1: VAE + llm embT + packed ctx_w transpose + loss partials ----
__global__ __launch_bounds__(64) void vae_kernel(
    const float* __restrict__ llms, const float* __restrict__ ctx_w,
    const float* __restrict__ fc1_w, const float* __restrict__ fc1_b,
    const float* __restrict__ fc21_w, const float* __restrict__ fc21_b,
    const float* __restrict__ fc22_w, const float* __restrict__ fc22_b,
    const float* __restrict__ fc3_w, const float* __restrict__ fc3_b,
    const float* __restrict__ fc4_w, const float* __restrict__ fc4_b,
    const float* __restrict__ eps,
    float* __restrict__ ctx_wP, float* __restrict__ embT,
    float* __restrict__ mse_row, float* __restrict__ kld_row)
{
    __shared__ __align__(16) float xs[D_IN];
    __shared__ __align__(16) float hs[HDIM];
    __shared__ __align__(16) float zs[HDIM];
    __shared__ __align__(16) float h2s[HDIM];
    const int r = blockIdx.x;
    const int j = threadIdx.x;

    // side job: pack-transpose ctx_w -> ctx_wP[(k4*64+j)*4+rr] = ctx_w[j*192+k4*4+rr]
    {
        int f = r * 64 + j;                       // [0, 16384); need [0, 12288)
        if (f < D_CTX * HDIM) {
            int p = f >> 2, rr = f & 3;
            int jc = p & 63, k4 = p >> 6;
            ctx_wP[f] = ctx_w[jc * D_CTX + k4 * 4 + rr];
        }
    }

    for (int k = j; k < D_IN; k += 64) xs[k] = llms[r * D_IN + k];
    __syncthreads();

    float acc = fc1_b[j];
    {
        const float4* wr = (const float4*)(fc1_w + (size_t)j * D_IN);
        const float4* xr = (const float4*)xs;
        #pragma unroll 8
        for (int k4 = 0; k4 < D_IN / 4; ++k4) { fma4(acc, wr[k4], xr[k4]); }
    }
    float h = fmaxf(acc, 0.0f);
    hs[j] = h;
    __syncthreads();

    float mu = fc21_b[j], lv = fc22_b[j];
    {
        const float4* w1 = (const float4*)(fc21_w + (size_t)j * HDIM);
        const float4* w2 = (const float4*)(fc22_w + (size_t)j * HDIM);
        const float4* hr = (const float4*)hs;
        #pragma unroll
        for (int k4 = 0; k4 < HDIM / 4; ++k4) {
            float4 hh = hr[k4];
            fma4(mu, w1[k4], hh);
            fma4(lv, w2[k4], hh);
        }
    }
    float stdv = expf(0.5f * lv) * 0.1f;
    float z = fmaf(eps[r * HDIM + j], stdv, mu);

    float elv = expf(lv);
    float kt = (1.0f - (-4.60517018598809136f)) + lv - (mu * mu + elv) / 0.01f;
    float ks = kt;
    #pragma unroll
    for (int o = 32; o; o >>= 1) ks += __shfl_xor(ks, o);

    float zsq = z * z;
    #pragma unroll
    for (int o = 32; o; o >>= 1) zsq += __shfl_xor(zsq, o);
    float nrm = fmaxf(sqrtf(zsq), 1e-12f);
    embT[j * N_L + r] = z / nrm;                 // transposed store (one-time scatter)
    zs[j] = z;
    __syncthreads();

    float a3 = fc3_b[j];
    {
        const float4* w3 = (const float4*)(fc3_w + (size_t)j * HDIM);
        const float4* zr = (const float4*)zs;
        #pragma unroll
        for (int k4 = 0; k4 < HDIM / 4; ++k4) { fma4(a3, w3[k4], zr[k4]); }
    }
    float h2 = fmaxf(a3, 0.0f);
    h2s[j] = h2;
    __syncthreads();

    float ms = 0.0f;
    const float4* h2r = (const float4*)h2s;
    #pragma unroll
    for (int m = 0; m < 6; ++m) {
        int o = j + 64 * m;
        float a4 = fc4_b[o];
        const float4* w4 = (const float4*)(fc4_w + (size_t)o * HDIM);
        #pragma unroll
        for (int k4 = 0; k4 < HDIM / 4; ++k4) { fma4(a4, w4[k4], h2r[k4]); }
        float d = a4 - xs[o];
        ms = fmaf(d, d, ms);
    }
    #pragma unroll
    for (int o = 32; o; o >>= 1) ms += __shfl_xor(ms, o);
    if (j == 0) { mse_row[r] = ms; kld_row[r] = ks; }
}

// ---------------- Kernel 2: FUSED routing ------------------------------------------------
// Round-0 LDS x-tile staging (coalesced 6 KB burst/wave, conflict-free broadcast reads)
// + round-1 VALU cuts: v_pk_fma_f32 in both GEMV phases, DPP reductions/scans (no
// ds_bpermute), e-strip overlaying the dead x region. Phase-2 per-component accumulation
// order is bit-identical to the two previous passing kernels.
__global__ __launch_bounds__(256) void route_kernel(
    const float* __restrict__ contexts, const float* __restrict__ ctx_wP, const float* __restrict__ ctx_b,
    const float* __restrict__ embT, const int* __restrict__ agent_num, const float* __restrict__ rand_u,
    const float* __restrict__ mse_row, const float* __restrict__ kld_row,
    float* __restrict__ out_sel, float* __restrict__ out_lp, float* __restrict__ out_loss)
{
    __shared__ __align__(16) float lds[4][1536];         // x-tile, e-strip overlays: 24 KB

    const int tid = threadIdx.x;
    const int lane = tid & 63;
    const int widx = tid >> 6;
    const int l0 = lane << 2;

    const int g = blockIdx.x * 4 + widx;                 // wave id [0, 8192)
    const int q0 = __builtin_amdgcn_readfirstlane(g << 3);
    float* myl = lds[widx];

    // ---- stage 8 context rows (6 KB contiguous, fully coalesced vector loads) ----
    {
        float4* xls = (float4*)myl;
        const float4* cbase = (const float4*)contexts + (size_t)q0 * (D_CTX / 4);
        #pragma unroll
        for (int it = 0; it < 6; ++it) {
            int f = lane + it * 64;                      // [0, 384)
            xls[f] = cbase[f];
        }
    }

    // ---- fold in vae_loss finalize (wave 0 only) ----
    if (g == 0) {
        int rr = lane * 4;
        float ms = mse_row[rr] + mse_row[rr + 1] + mse_row[rr + 2] + mse_row[rr + 3];
        float ks = kld_row[rr] + kld_row[rr + 1] + kld_row[rr + 2] + kld_row[rr + 3];
        #pragma unroll
        for (int o = 32; o; o >>= 1) { ms += __shfl_xor(ms, o); ks += __shfl_xor(ks, o); }
        if (lane == 0) out_loss[0] = ms / 98304.0f - 0.5f * (ks / 16384.0f);
    }

    // ---- agent counts: wave-uniform index -> scalar loads ----
    int Aq[8];
    #pragma unroll
    for (int q = 0; q < 8; ++q) Aq[q] = agent_num[q0 + q];

    // ---- phase 1: e_j (lane j) for 8 queries; w coalesced b128, x uniform LDS broadcast,
    //      packed fp32 FMAs (even/odd k split) ----
    const float bj = ctx_b[lane];
    v2f acc[8];
    #pragma unroll
    for (int q = 0; q < 8; ++q) acc[q] = mk2(bj, 0.0f);
    {
        const float4* wp = (const float4*)ctx_wP;
        const float4* xls = (const float4*)myl;
        #pragma unroll 2
        for (int k4 = 0; k4 < D_CTX / 4; ++k4) {
            float4 w = wp[k4 * HDIM + lane];             // lane-coalesced 1 KB load
            v2f w01 = mk2(w.x, w.y), w23 = mk2(w.z, w.w);
            #pragma unroll
            for (int q = 0; q < 8; ++q) {
                float4 xv = xls[q * 48 + k4];            // uniform broadcast ds_read_b128
                acc[q] = __builtin_elementwise_fma(w01, mk2(xv.x, xv.y), acc[q]);
                acc[q] = __builtin_elementwise_fma(w23, mk2(xv.z, xv.w), acc[q]);
            }
        }
    }
    float e[8];
    #pragma unroll
    for (int q = 0; q < 8; ++q) e[q] = acc[q].x + acc[q].y;
    #pragma unroll
    for (int q = 0; q < 8; ++q) {
        float s = bc63(wave_iscan(e[q] * e[q]));         // wave sum via DPP -> SGPR
        e[q] *= 1.0f / fmaxf(sqrtf(s), 1e-12f);
        myl[q * HDIM + lane] = e[q];                     // e-strip overlays dead x region
    }

    // ---- phase 2: logits, lane's 4 llms x 8 queries; packed fp32, op_sel e-broadcast ----
    v2f Pa[8], Pb[8];                                    // (l0,l0+1) and (l0+2,l0+3)
    #pragma unroll
    for (int q = 0; q < 8; ++q) { Pa[q] = mk2(0.0f, 0.0f); Pb[q] = mk2(0.0f, 0.0f); }

    #pragma unroll 2
    for (int j4 = 0; j4 < HDIM / 4; ++j4) {
        float4 M0 = *(const float4*)(embT + (size_t)(j4 * 4 + 0) * N_L + l0);  // coalesced
        float4 M1 = *(const float4*)(embT + (size_t)(j4 * 4 + 1) * N_L + l0);
        float4 M2 = *(const float4*)(embT + (size_t)(j4 * 4 + 2) * N_L + l0);
        float4 M3 = *(const float4*)(embT + (size_t)(j4 * 4 + 3) * N_L + l0);
        v2f m0a = mk2(M0.x, M0.y), m0b = mk2(M0.z, M0.w);
        v2f m1a = mk2(M1.x, M1.y), m1b = mk2(M1.z, M1.w);
        v2f m2a = mk2(M2.x, M2.y), m2b = mk2(M2.z, M2.w);
        v2f m3a = mk2(M3.x, M3.y), m3b = mk2(M3.z, M3.w);
        #pragma unroll
        for (int q = 0; q < 8; ++q) {
            float4 ev = *(const float4*)(myl + q * HDIM + j4 * 4);   // uniform LDS broadcast
            v2f e01 = mk2(ev.x, ev.y), e23 = mk2(ev.z, ev.w);
            // per-component order identical to prior rounds: M0*ev.x, M1*ev.y, M2*ev.z, M3*ev.w
            pk_fma_lo(Pa[q], m0a, e01);
            pk_fma_hi(Pa[q], m1a, e01);
            pk_fma_lo(Pa[q], m2a, e23);
            pk_fma_hi(Pa[q], m3a, e23);
            pk_fma_lo(Pb[q], m0b, e01);
            pk_fma_hi(Pb[q], m1b, e01);
            pk_fma_lo(Pb[q], m2b, e23);
            pk_fma_hi(Pb[q], m3b, e23);
        }
    }

    float4 P[8];
    #pragma unroll
    for (int k = 0; k < 8; ++k) P[k] = make_float4(Pa[k].x, Pa[k].y, Pb[k].x, Pb[k].y);

    // ---- softmax (DPP max/sum; same per-query op order) ----
    #pragma unroll
    for (int k = 0; k < 8; ++k) {
        float m = fmaxf(fmaxf(P[k].x, P[k].y), fmaxf(P[k].z, P[k].w));
        m = bc63(wave_max_l63(m));                       // exact wave max
        P[k].x = expf(P[k].x - m); P[k].y = expf(P[k].y - m);
        P[k].z = expf(P[k].z - m); P[k].w = expf(P[k].w - m);
        float s = bc63(wave_iscan(P[k].x + P[k].y + P[k].z + P[k].w));
        float inv = 1.0f / s;
        P[k].x *= inv; P[k].y *= inv; P[k].z *= inv; P[k].w *= inv;
    }

    // ---- inclusive cumsum via DPP scan ----
    float c0[8], c1[8], c2[8], c3[8];
    #pragma unroll
    for (int k = 0; k < 8; ++k) {
        c0[k] = P[k].x; c1[k] = c0[k] + P[k].y; c2[k] = c1[k] + P[k].z;
        float p3 = c2[k] + P[k].w;
        float t = wave_iscan(p3);
        float base = t - p3;
        c0[k] += base; c1[k] += base; c2[k] += base; c3[k] = p3 + base;
    }

    // ---- sampling: ballot+popcount; u via wave-uniform scalar load ----
    unsigned nib[8] = {0, 0, 0, 0, 0, 0, 0, 0};
    #pragma unroll
    for (int i = 0; i < MAXA; ++i) {
        #pragma unroll
        for (int k = 0; k < 8; ++k) {
            if (i < Aq[k]) {                       // wave-uniform scalar branch
                float u = rand_u[(size_t)i * N_Q + q0 + k];   // uniform -> s_load
                unsigned long long b0 = __ballot(c0[k] <= u);
                unsigned long long b1 = __ballot(c1[k] <= u);
                unsigned long long b2 = __ballot(c2[k] <= u);
                unsigned long long b3 = __ballot(c3[k] <= u);
                int loc = __popcll(b0) + __popcll(b1) + __popcll(b2) + __popcll(b3);
                int sel = (loc >= N_L) ? 0 : loc;  // numpy argmax(all-False) == 0
                unsigned d = (unsigned)(sel - l0);
                if (d < 4u) nib[k] += 1u << (4 * d);
            }
        }
    }

    // ---- row stores + log-prob terms (same per-query arithmetic/order) ----
    float term[8];
    #pragma unroll
    for (int k = 0; k < 8; ++k) {
        int n0 = nib[k] & 15, n1 = (nib[k] >> 4) & 15, n2 = (nib[k] >> 8) & 15, n3 = (nib[k] >> 12) & 15;
        float4 rowv = make_float4((float)n0, (float)n1, (float)n2, (float)n3);
        *(((float4*)(out_sel + (size_t)(q0 + k) * N_L)) + lane) = rowv;
        float tm = 0.0f;
        if (n0) tm += (float)n0 * logf(P[k].x) - lgfact(n0);
        if (n1) tm += (float)n1 * logf(P[k].y) - lgfact(n1);
        if (n2) tm += (float)n2 * logf(P[k].z) - lgfact(n2);
        if (n3) tm += (float)n3 * logf(P[k].w) - lgfact(n3);
        term[k] = tm;
    }
    float st[8];
    #pragma unroll
    for (int k = 0; k < 8; ++k) st[k] = bc63(wave_iscan(term[k]));

    if (lane < 8) {
        float rr = st[0];
        int Aa = Aq[0];
        #pragma unroll
        for (int k = 1; k < 8; ++k) {
            if (lane == k) { rr = st[k]; Aa = Aq[k]; }
        }
        out_lp[q0 + lane] = lgfact(Aa) + rr;
    }
}

extern "C" void kernel_launch(void* const* d_in, const int* in_sizes, int n_in,
                              void* d_out, int out_size, void* d_ws, size_t ws_size,
                              hipStream_t stream) {
    const float* llms      = (const float*)d_in[0];
    const float* contexts  = (const float*)d_in[1];
    const int*   agent_i   = (const int*)  d_in[2];
    // d_in[3] agent_num_float unused (int version + table)
    const float* fc1_w  = (const float*)d_in[4];  const float* fc1_b  = (const float*)d_in[5];
    const float* fc21_w = (const float*)d_in[6];  const float* fc21_b = (const float*)d_in[7];
    const float* fc22_w = (const float*)d_in[8];  const float* fc22_b = (const float*)d_in[9];
    const float* fc3_w  = (const float*)d_in[10]; const float* fc3_b  = (const float*)d_in[11];
    const float* fc4_w  = (const float*)d_in[12]; const float* fc4_b  = (const float*)d_in[13];
    const float* ctx_w  = (const float*)d_in[14]; const float* ctx_b  = (const float*)d_in[15];
    const float* noise  = (const float*)d_in[16]; const float* rand_u = (const float*)d_in[17];

    float* out      = (float*)d_out;
    float* out_sel  = out;                          // [65536][256]
    float* out_lp   = out + (size_t)N_Q * N_L;      // [65536]
    float* out_loss = out_lp + N_Q;                 // [1]

    float* ctx_wP   = (float*)d_ws;                 // [48][64] float4 (12288 floats)
    float* embT     = ctx_wP + D_CTX * HDIM;        // [64][256]
    float* mse_row  = embT + HDIM * N_L;            // [256]
    float* kld_row  = mse_row + N_L;                // [256]

    vae_kernel<<<N_L, 64, 0, stream>>>(llms, ctx_w, fc1_w, fc1_b, fc21_w, fc21_b, fc22_w, fc22_b,
                                       fc3_w, fc3_b, fc4_w, fc4_b, noise,
                                       ctx_wP, embT, mse_row, kld_row);
    route_kernel<<<2048, 256, 0, stream>>>(contexts, ctx_wP, ctx_b, embT, agent_i, rand_u,
                                           mse_row, kld_row, out_sel, out_lp, out_loss);
}